// Round 5
// baseline (938.688 us; speedup 1.0000x reference)
//
#include <hip/hip_runtime.h>
#include <hip/hip_bf16.h>
#include <stdint.h>

typedef unsigned short u16;
typedef u16   u16x8 __attribute__((ext_vector_type(8)));
typedef short s16x8 __attribute__((ext_vector_type(8)));
typedef float f32x4 __attribute__((ext_vector_type(4)));

#define TOKENS 51200
#define DMODEL 1024
#define DINNER 2048
#define NSTATE 16
#define SEQLEN 100

// workspace layout (bytes)
#define OFF_XP    0ull          // 51200*1024*2   = 104857600
#define OFF_WCAT  104857600ull  // W2T: 128*4096*8*2 = 8388608
#define OFF_WB    113246208ull  // 16*2048*2      =     65536
#define OFF_WC    113311744ull  // 16*1024*2      =     32768
#define OFF_BPART 113344512ull  // 16*51200*16*4  =  52428800
#define OFF_BFIN  165773312ull  // 51200*16*4     =   3276800
#define OFF_CBUF  169050112ull  // 51200*16*4
#define OFF_Y     172326912ull  // 51200*16*4     -> total 175603712 bytes

__device__ __forceinline__ u16 f2b(float f) {  // f32 -> bf16 RNE
  uint32_t u = __float_as_uint(f);
  uint32_t r = (u + 0x7fffu + ((u >> 16) & 1u)) >> 16;
  return (u16)r;
}
__device__ __forceinline__ float b2f(u16 u) {
  return __uint_as_float(((uint32_t)u) << 16);
}

#define GLL(gp, lp) __builtin_amdgcn_global_load_lds( \
    (__attribute__((address_space(1))) unsigned int*)(gp), \
    (__attribute__((address_space(3))) unsigned int*)(lp), 16, 0, 0)

// ---------------- prep: XP = bf16(x + pos_emb) ----------------
__global__ void k_prep_x(const float* __restrict__ x, const float* __restrict__ pos,
                         u16* __restrict__ xp) {
  long e = ((long)blockIdx.x * blockDim.x + threadIdx.x) * 8;
  int d = (int)(e & (DMODEL - 1));
  long tok = e >> 10;
  int s = (int)(tok % SEQLEN);
  f32x4 a0 = *(const f32x4*)(x + e);
  f32x4 a1 = *(const f32x4*)(x + e + 4);
  f32x4 p0 = *(const f32x4*)(pos + (size_t)s * DMODEL + d);
  f32x4 p1 = *(const f32x4*)(pos + (size_t)s * DMODEL + d + 4);
  u16x8 o;
  o[0] = f2b(a0[0] + p0[0]); o[1] = f2b(a0[1] + p0[1]);
  o[2] = f2b(a0[2] + p0[2]); o[3] = f2b(a0[3] + p0[3]);
  o[4] = f2b(a1[0] + p1[0]); o[5] = f2b(a1[1] + p1[1]);
  o[6] = f2b(a1[2] + p1[2]); o[7] = f2b(a1[3] + p1[3]);
  *(u16x8*)(xp + e) = o;
}

// ---------------- prep: W2T = bf16 transposed row-interleaved [Win;Wg] ----------------
// Combined col g (g = 32q+r): r<16 -> Win row 16q+r, else Wg row 16q+r-16.
// Layout: W2T[k8][g][8], element (k8,g,j) = Wcomb[g][k8*8+j].
__global__ void k_prep_w(const float* __restrict__ Win, const float* __restrict__ Wg,
                         u16* __restrict__ w2t) {
  long e = ((long)blockIdx.x * blockDim.x + threadIdx.x) * 8;  // < 4194304
  int k8 = (int)(e >> 15);
  int g  = (int)((e >> 3) & 4095);
  int srow = ((g >> 5) << 4) + (g & 15);
  const float* src = ((g & 16) ? Wg : Win) + (size_t)srow * DMODEL + (k8 << 3);
  f32x4 a0 = *(const f32x4*)src;
  f32x4 a1 = *(const f32x4*)(src + 4);
  u16x8 o;
  o[0] = f2b(a0[0]); o[1] = f2b(a0[1]); o[2] = f2b(a0[2]); o[3] = f2b(a0[3]);
  o[4] = f2b(a1[0]); o[5] = f2b(a1[1]); o[6] = f2b(a1[2]); o[7] = f2b(a1[3]);
  *(u16x8*)(w2t + e) = o;
}

// ---------------- prep: W_B, W_C -> bf16 ----------------
__global__ void k_prep_wbc(const float* __restrict__ WB, const float* __restrict__ WC,
                           u16* __restrict__ wb, u16* __restrict__ wc) {
  long e = ((long)blockIdx.x * blockDim.x + threadIdx.x) * 8;  // < 49152
  const float* src; u16* dst;
  if (e < 32768) { src = WB + e; dst = wb + e; }
  else           { src = WC + (e - 32768); dst = wc + (e - 32768); }
  f32x4 a0 = *(const f32x4*)src;
  f32x4 a1 = *(const f32x4*)(src + 4);
  u16x8 o;
  o[0] = f2b(a0[0]); o[1] = f2b(a0[1]); o[2] = f2b(a0[2]); o[3] = f2b(a0[3]);
  o[4] = f2b(a1[0]); o[5] = f2b(a1[1]); o[6] = f2b(a1[2]); o[7] = f2b(a1[3]);
  *(u16x8*)(dst) = o;
}

// ============ fused dual GEMM: 256x256, BK=64, A-in-LDS (2x32KB), B-regs from L2 ============
// 512 threads = 8 waves (2M x 4N); per-wave C = 128x64 (8m x 4n 16x16x32 frags).
// Per K-tile t: vmcnt(8); s_barrier; ds_read A ks0; GLL A(t+1) x4; [fence] plain-load B(t+1) x8;
// 32 MFMA ks0; ds_read A ks1; 32 MFMA ks1.  B loads are compiler-tracked (counted waits, no drain).
__global__ __launch_bounds__(512, 2) void k_gemm256(
    const u16* __restrict__ XP, const u16* __restrict__ W2T, const u16* __restrict__ WBb,
    const float* __restrict__ b_in, const float* __restrict__ b_gate,
    float* __restrict__ Bpart) {
  extern __shared__ __align__(16) u16 smem[];
  char* smemc = (char*)smem;

  const int tid = threadIdx.x;
  const int bid = blockIdx.x;
  // XCD-affine swizzle: XCD owns nb pairs {2x,2x+1}
  const int nb = ((bid & 7) << 1) | ((bid >> 3) & 1);  // 0..15
  const int rb = bid >> 4;                             // 0..199
  const int m0 = rb << 8;
  const int n0 = nb << 8;

  // --- A staging: thread -> row tid>>3 (+64/round), chunk tid&7 (inverse-swizzled source) ---
  const int srowL = tid >> 3;                          // 0..63
  const int csrc  = (tid & 7) ^ (srowL & 7);
  const u16* gA = XP + (size_t)(m0 + srowL) * DMODEL + (csrc << 3);
  const int ldst = tid << 4;                           // byte offset in 8KB round

  const int wid = tid >> 6, lane = tid & 63;
  const int wm = wid >> 2, wn = wid & 3;
  const int l15 = lane & 15, lhi = lane >> 4;

  // --- A-frag read: row = wm*128 + m*16 + l15 (128B rows), chunk = (ks*4+lhi) ^ (l15&7) ---
  const int abyte = ((wm << 7) + l15) * 128 + ((lhi ^ (l15 & 7)) << 4);  // ks1: ^64; m: +m<<11

  // --- B global base (u16 elems): ((lhi)*4096 + n0 + wn*64 + l15) * 8 ---
  const size_t bbase = ((size_t)lhi * 4096 + (size_t)(n0 + (wn << 6) + l15)) * 8;

  f32x4 acc[8][4] = {};
  s16x8 B0[8], B1[8];

#define STGA(t) do { \
    char* d_ = smemc + (((t) & 1) << 15); \
    const u16* g_ = gA + ((t) << 6); \
    GLL(g_,          d_ + ldst); \
    GLL(g_ + 65536,  d_ + 8192  + ldst); \
    GLL(g_ + 131072, d_ + 16384 + ldst); \
    GLL(g_ + 196608, d_ + 24576 + ldst); \
  } while (0)

#define LOADB(Bv, t) do { \
    const u16* bp_ = W2T + bbase + (size_t)(t) * 262144; \
    _Pragma("unroll") \
    for (int ks_ = 0; ks_ < 2; ++ks_) { \
      _Pragma("unroll") \
      for (int n_ = 0; n_ < 4; ++n_) \
        Bv[ks_ * 4 + n_] = *(const s16x8*)(bp_ + ks_ * 131072 + n_ * 128); \
    } \
  } while (0)

  auto ITER = [&](int t, s16x8 (&Bc)[8], s16x8 (&Bn)[8]) {
    if (t == 15) asm volatile("s_waitcnt vmcnt(0)" ::: "memory");
    else         asm volatile("s_waitcnt vmcnt(8)" ::: "memory");
    __builtin_amdgcn_sched_barrier(0);
    asm volatile("s_barrier" ::: "memory");
    __builtin_amdgcn_sched_barrier(0);

    const char* ab = smemc + ((t & 1) << 15);
    s16x8 a[8];
#pragma unroll
    for (int m = 0; m < 8; ++m) a[m] = *(const s16x8*)(ab + abyte + (m << 11));
    if (t < 15) STGA(t + 1);          // A(t+1) GLLs issued BEFORE B(t+1) loads
    __builtin_amdgcn_sched_barrier(0);
    if (t < 15) LOADB(Bn, t + 1);     // compiler-tracked; counted wait before use next iter
    __builtin_amdgcn_s_setprio(1);
#pragma unroll
    for (int m = 0; m < 8; ++m)
#pragma unroll
      for (int n = 0; n < 4; ++n)
        acc[m][n] = __builtin_amdgcn_mfma_f32_16x16x32_bf16(a[m], Bc[n], acc[m][n], 0, 0, 0);
    __builtin_amdgcn_s_setprio(0);
#pragma unroll
    for (int m = 0; m < 8; ++m) a[m] = *(const s16x8*)(ab + (abyte ^ 64) + (m << 11));
    __builtin_amdgcn_s_setprio(1);
#pragma unroll
    for (int m = 0; m < 8; ++m)
#pragma unroll
      for (int n = 0; n < 4; ++n)
        acc[m][n] = __builtin_amdgcn_mfma_f32_16x16x32_bf16(a[m], Bc[4 + n], acc[m][n], 0, 0, 0);
    __builtin_amdgcn_s_setprio(0);
  };

  // prologue: A(0) GLLs then B(0) loads (order pinned for the vmcnt(8) count)
  STGA(0);
  __builtin_amdgcn_sched_barrier(0);
  LOADB(B0, 0);

#pragma unroll 1
  for (int tt = 0; tt < 8; ++tt) {
    ITER(2 * tt, B0, B1);
    ITER(2 * tt + 1, B1, B0);
  }
#undef STGA
#undef LOADB

  asm volatile("s_waitcnt lgkmcnt(0)" ::: "memory");
  asm volatile("s_barrier" ::: "memory");

  // --- epilogue: in-register gating (acc[m][2u]=proj, acc[m][2u+1]=gate) ---
  u16* xg = smem;  // [256][136] bf16 (+8 pad), 69632 B
  float bi[2], bg[2];
#pragma unroll
  for (int u = 0; u < 2; ++u) {
    const int gcol = (nb << 7) + (((wn << 1) + u) << 4) + l15;
    bi[u] = b_in[gcol];
    bg[u] = b_gate[gcol];
  }
#pragma unroll
  for (int m = 0; m < 8; ++m)
#pragma unroll
    for (int u = 0; u < 2; ++u)
#pragma unroll
      for (int j = 0; j < 4; ++j) {
        const int row = (wm << 7) + (m << 4) + (lhi << 2) + j;
        const int col = (((wn << 1) + u) << 4) + l15;
        float pv = acc[m][2 * u][j] + bi[u];
        float gv = acc[m][2 * u + 1][j] + bg[u];
        xg[row * 136 + col] = f2b(pv / (1.0f + __expf(-gv)));
      }
  asm volatile("s_waitcnt lgkmcnt(0)" ::: "memory");
  asm volatile("s_barrier" ::: "memory");

  // --- mini-GEMM: Bpart[nb][m0+row][state] = xg @ W_B[:, nb*128..+128]^T ---
  f32x4 bacc[2] = {};
#pragma unroll
  for (int m2 = 0; m2 < 2; ++m2)
#pragma unroll
    for (int kc = 0; kc < 4; ++kc) {
      s16x8 av = *(const s16x8*)(xg + ((wid << 5) + (m2 << 4) + l15) * 136 + (kc << 5) + (lhi << 3));
      s16x8 bv = *(const s16x8*)(WBb + (size_t)l15 * DINNER + (nb << 7) + (kc << 5) + (lhi << 3));
      bacc[m2] = __builtin_amdgcn_mfma_f32_16x16x32_bf16(av, bv, bacc[m2], 0, 0, 0);
    }
#pragma unroll
  for (int m2 = 0; m2 < 2; ++m2) {
    float* outp = Bpart + ((size_t)nb * TOKENS + m0 + (wid << 5) + (m2 << 4) + (lhi << 2)) * NSTATE + l15;
#pragma unroll
    for (int j = 0; j < 4; ++j) outp[j * NSTATE] = bacc[m2][j];
  }
}

// ---------------- C = XP @ W_C^T + b_C (MFMA; W_C staged once in LDS) ----------------
// 256 threads = 4 waves; block = 64 rows; 32 MFMAs per wave over K=1024.
__global__ __launch_bounds__(256) void k_C(const u16* __restrict__ XP, const u16* __restrict__ WC,
                                           const float* __restrict__ bC, float* __restrict__ Cb) {
  __shared__ __align__(16) u16 wcl[16 * 1032];  // rows padded +8 elems (2-way banks max)
  const int tid = threadIdx.x;
  const int m0 = blockIdx.x << 6;
#pragma unroll
  for (int i = 0; i < 8; ++i) {
    int c = i * 256 + tid;                       // 16B chunk id, 0..2047
    int row = c >> 7, col = c & 127;
    *(u16x8*)(wcl + row * 1032 + (col << 3)) = *(const u16x8*)(WC + (row << 10) + (col << 3));
  }
  __syncthreads();
  const int wv = tid >> 6, lane = tid & 63;
  const int l15 = lane & 15, lhi = lane >> 4;
  const u16* xr = XP + (size_t)(m0 + (wv << 4) + l15) * DMODEL + (lhi << 3);
  const u16* wr = wcl + l15 * 1032 + (lhi << 3);
  f32x4 acc = {};
#pragma unroll
  for (int t = 0; t < 32; ++t) {
    s16x8 av = *(const s16x8*)(xr + t * 32);
    s16x8 bv = *(const s16x8*)(wr + t * 32);
    acc = __builtin_amdgcn_mfma_f32_16x16x32_bf16(av, bv, acc, 0, 0, 0);
  }
  const float bc = bC[l15];
  float* o = Cb + (size_t)(m0 + (wv << 4) + (lhi << 2)) * NSTATE + l15;
#pragma unroll
  for (int j = 0; j < 4; ++j) o[j * NSTATE] = acc[j] + bc;
}

// ---------------- B = sum_chunks Bpart + b_B ----------------
__global__ void k_finB(const float* __restrict__ Bpart, const float* __restrict__ bB,
                       float* __restrict__ Bf) {
  const long i = (long)blockIdx.x * blockDim.x + threadIdx.x;  // per float4
  f32x4 s = {};
#pragma unroll
  for (int cb = 0; cb < 16; ++cb)
    s += *(const f32x4*)(Bpart + (size_t)cb * (TOKENS * NSTATE) + i * 4);
  s += *(const f32x4*)(bB + ((i & 3) << 2));
  *(f32x4*)(Bf + i * 4) = s;
}

// ---------------- sequential scan: h = A*h + B; y = h*C ----------------
__global__ void k_scan(const float* __restrict__ Bf, const float* __restrict__ Cb,
                       const float* __restrict__ Alog, float* __restrict__ Y) {
  const int t = threadIdx.x;
  const int b = blockIdx.x * 16 + (t >> 4);
  const int n = t & 15;
  const float A = __expf(0.01f * __expf(Alog[n]));
  float h = 0.f;
  const size_t base = (size_t)b * SEQLEN * NSTATE + n;
  for (int s = 0; s < SEQLEN; ++s) {
    const size_t idx = base + (size_t)s * NSTATE;
    h = A * h + Bf[idx];
    Y[idx] = h * Cb[idx];
  }
}

// ---------------- out = Y @ W_out[:, :16]^T + b_out ----------------
__global__ __launch_bounds__(256) void k_out(const float* __restrict__ Y,
                                             const float* __restrict__ Wout,
                                             const float* __restrict__ bout,
                                             float* __restrict__ out) {
  __shared__ float ys[32][16];
  const int tid = threadIdx.x;
  const long t0 = (long)blockIdx.x * 32;
  for (int i = tid; i < 512; i += 256) ys[i >> 4][i & 15] = Y[t0 * 16 + i];
  const int d0 = tid << 2;
  float w[4][16];
#pragma unroll
  for (int j = 0; j < 4; ++j)
#pragma unroll
    for (int q = 0; q < 4; ++q) {
      f32x4 wv = *(const f32x4*)(Wout + (size_t)(d0 + j) * DINNER + q * 4);
#pragma unroll
      for (int e = 0; e < 4; ++e) w[j][q * 4 + e] = wv[e];
    }
  f32x4 bo = *(const f32x4*)(bout + d0);
  __syncthreads();
  for (int r = 0; r < 32; ++r) {
    f32x4 acc = bo;
#pragma unroll
    for (int n = 0; n < 16; ++n) {
      const float yv = ys[r][n];
      acc[0] += yv * w[0][n];
      acc[1] += yv * w[1][n];
      acc[2] += yv * w[2][n];
      acc[3] += yv * w[3][n];
    }
    *(f32x4*)(out + (t0 + r) * 1024 + d0) = acc;
  }
}

extern "C" void kernel_launch(void* const* d_in, const int* in_sizes, int n_in,
                              void* d_out, int out_size, void* d_ws, size_t ws_size,
                              hipStream_t stream) {
  const float* x    = (const float*)d_in[0];
  const float* pos  = (const float*)d_in[1];
  const float* Win  = (const float*)d_in[2];
  const float* bin  = (const float*)d_in[3];
  const float* Wg   = (const float*)d_in[4];
  const float* bg   = (const float*)d_in[5];
  const float* Alog = (const float*)d_in[6];
  const float* WB   = (const float*)d_in[7];
  const float* bB   = (const float*)d_in[8];
  const float* WC   = (const float*)d_in[9];
  const float* bC   = (const float*)d_in[10];
  const float* Wout = (const float*)d_in[11];
  const float* bout = (const float*)d_in[12];

  char* ws = (char*)d_ws;
  u16*   XP   = (u16*)(ws + OFF_XP);
  u16*   W2T  = (u16*)(ws + OFF_WCAT);
  u16*   WBb  = (u16*)(ws + OFF_WB);
  u16*   WCb  = (u16*)(ws + OFF_WC);
  float* BP   = (float*)(ws + OFF_BPART);
  float* BF   = (float*)(ws + OFF_BFIN);
  float* CB   = (float*)(ws + OFF_CBUF);
  float* Yb   = (float*)(ws + OFF_Y);

  hipFuncSetAttribute((const void*)k_gemm256,
                      hipFuncAttributeMaxDynamicSharedMemorySize, 69632);

  k_prep_x  <<<25600, 256, 0, stream>>>(x, pos, XP);
  k_prep_w  <<<2048, 256, 0, stream>>>(Win, Wg, W2T);
  k_prep_wbc<<<24, 256, 0, stream>>>(WB, WC, WBb, WCb);
  k_gemm256 <<<3200, 512, 69632, stream>>>(XP, W2T, WBb, bin, bg, BP);
  k_C       <<<800, 256, 0, stream>>>(XP, WCb, bC, CB);
  k_finB    <<<800, 256, 0, stream>>>(BP, bB, BF);
  k_scan    <<<32, 256, 0, stream>>>(BF, CB, Alog, Yb);
  k_out     <<<1600, 256, 0, stream>>>(Yb, Wout, bout, (float*)d_out);
}

// Round 7
// 565.338 us; speedup vs baseline: 1.6604x; 1.6604x over previous
//
#include <hip/hip_runtime.h>
#include <hip/hip_bf16.h>
#include <stdint.h>

typedef unsigned short u16;
typedef u16   u16x8 __attribute__((ext_vector_type(8)));
typedef short s16x8 __attribute__((ext_vector_type(8)));
typedef float f32x4 __attribute__((ext_vector_type(4)));

#define TOKENS 51200
#define DMODEL 1024
#define DINNER 2048
#define NSTATE 16
#define SEQLEN 100

// workspace layout (bytes)
#define OFF_XP    0ull          // 51200*1024*2   = 104857600
#define OFF_WCAT  104857600ull  // W2: 4096*1024*2 = 8388608
#define OFF_WB    113246208ull  // 16*2048*2      =     65536
#define OFF_WC    113311744ull  // 16*1024*2      =     32768
#define OFF_BPART 113344512ull  // 16*51200*16*4  =  52428800
#define OFF_BFIN  165773312ull  // 51200*16*4     =   3276800
#define OFF_CBUF  169050112ull  // 51200*16*4
#define OFF_Y     172326912ull  // 51200*16*4     -> total 175603712 bytes

__device__ __forceinline__ u16 f2b(float f) {  // f32 -> bf16 RNE
  uint32_t u = __float_as_uint(f);
  uint32_t r = (u + 0x7fffu + ((u >> 16) & 1u)) >> 16;
  return (u16)r;
}
__device__ __forceinline__ float b2f(u16 u) {
  return __uint_as_float(((uint32_t)u) << 16);
}

#define GLL(gp, lp) __builtin_amdgcn_global_load_lds( \
    (__attribute__((address_space(1))) unsigned int*)(gp), \
    (__attribute__((address_space(3))) unsigned int*)(lp), 16, 0, 0)
#define SB0() __builtin_amdgcn_sched_barrier(0)

// ---------------- prep: XP = bf16(x + pos_emb) ----------------
__global__ void k_prep_x(const float* __restrict__ x, const float* __restrict__ pos,
                         u16* __restrict__ xp) {
  long e = ((long)blockIdx.x * blockDim.x + threadIdx.x) * 8;
  int d = (int)(e & (DMODEL - 1));
  long tok = e >> 10;
  int s = (int)(tok % SEQLEN);
  f32x4 a0 = *(const f32x4*)(x + e);
  f32x4 a1 = *(const f32x4*)(x + e + 4);
  f32x4 p0 = *(const f32x4*)(pos + (size_t)s * DMODEL + d);
  f32x4 p1 = *(const f32x4*)(pos + (size_t)s * DMODEL + d + 4);
  u16x8 o;
  o[0] = f2b(a0[0] + p0[0]); o[1] = f2b(a0[1] + p0[1]);
  o[2] = f2b(a0[2] + p0[2]); o[3] = f2b(a0[3] + p0[3]);
  o[4] = f2b(a1[0] + p1[0]); o[5] = f2b(a1[1] + p1[1]);
  o[6] = f2b(a1[2] + p1[2]); o[7] = f2b(a1[3] + p1[3]);
  *(u16x8*)(xp + e) = o;
}

// ---------------- prep: W2 = bf16 row-interleaved [Win;Wg] (row-major) ----------------
// W2 row r (r = 32j+k): k<16 -> Win[16j+k], else Wg[16j+k-16].
__global__ void k_prep_w(const float* __restrict__ Win, const float* __restrict__ Wg,
                         u16* __restrict__ w2) {
  long e = ((long)blockIdx.x * blockDim.x + threadIdx.x) * 8;  // < 4194304
  int r = (int)(e >> 10), c = (int)(e & 1023);
  int srow = ((r >> 5) << 4) + (r & 15);
  const float* src = ((r & 16) ? Wg : Win) + (size_t)srow * DMODEL + c;
  f32x4 a0 = *(const f32x4*)src;
  f32x4 a1 = *(const f32x4*)(src + 4);
  u16x8 o;
  o[0] = f2b(a0[0]); o[1] = f2b(a0[1]); o[2] = f2b(a0[2]); o[3] = f2b(a0[3]);
  o[4] = f2b(a1[0]); o[5] = f2b(a1[1]); o[6] = f2b(a1[2]); o[7] = f2b(a1[3]);
  *(u16x8*)(w2 + e) = o;
}

// ---------------- prep: W_B, W_C -> bf16 ----------------
__global__ void k_prep_wbc(const float* __restrict__ WB, const float* __restrict__ WC,
                           u16* __restrict__ wb, u16* __restrict__ wc) {
  long e = ((long)blockIdx.x * blockDim.x + threadIdx.x) * 8;  // < 49152
  const float* src; u16* dst;
  if (e < 32768) { src = WB + e; dst = wb + e; }
  else           { src = WC + (e - 32768); dst = wc + (e - 32768); }
  f32x4 a0 = *(const f32x4*)src;
  f32x4 a1 = *(const f32x4*)(src + 4);
  u16x8 o;
  o[0] = f2b(a0[0]); o[1] = f2b(a0[1]); o[2] = f2b(a0[2]); o[3] = f2b(a0[3]);
  o[4] = f2b(a1[0]); o[5] = f2b(a1[1]); o[6] = f2b(a1[2]); o[7] = f2b(a1[3]);
  *(u16x8*)(dst) = o;
}

// ============ fused dual GEMM (R2-verified skeleton + interleaved issue) ============
// 256x256 tile, BK=64, 512 threads = 8 waves (2M x 4N), per-wave C = 128x64 (acc[8][4]).
// LDS 128KB: 2 bufs x {A 32KB, B 32KB}. Depth-2 staging: STAGE(t+2) issued after the
// mid-tile lgkmcnt(0)+barrier (buffer provably free); vmcnt(8) at tile start is counted
// (steady-state no-op). Staging GLLs spread into 4 slots between post-mid MFMA clusters.
__global__ __launch_bounds__(512, 2) void k_gemm256(
    const u16* __restrict__ XP, const u16* __restrict__ W2, const u16* __restrict__ WBb,
    const float* __restrict__ b_in, const float* __restrict__ b_gate,
    float* __restrict__ Bpart) {
  extern __shared__ __align__(16) u16 smem[];
  char* smemc = (char*)smem;

  const int tid = threadIdx.x;
  const int bid = blockIdx.x;
  // XCD-affine swizzle: XCD owns nb pairs {2x,2x+1} -> its 1MB of W2 stays L2-resident
  const int nb = ((bid & 7) << 1) | ((bid >> 3) & 1);  // 0..15
  const int rb = bid >> 4;                             // 0..199
  const int m0 = rb << 8;
  const int n0 = nb << 8;

  // --- staging addresses (R2-verified): row tid>>3, chunk (tid&7) inverse-swizzled ---
  const int arow  = tid >> 3;                              // 0..63
  const int acolsw = ((tid & 7) ^ (arow & 7)) << 3;
  const u16* gA = XP + (size_t)(m0 + arow) * DMODEL + acolsw;
  const u16* gB = W2 + (size_t)(n0 + arow) * DMODEL + acolsw;
  const int ldst = tid << 3;                               // u16 offset (16B/thread)

  // --- wave/frag constants (R2-verified) ---
  const int wid = tid >> 6, lane = tid & 63;
  const int wm = wid >> 2, wn = wid & 3;
  const int l15 = lane & 15, lhi = lane >> 4;
  const int swz = (l15 & 7) << 4;
  const int arow0 = (wm << 7) + l15;
  const int brow0 = (wn << 6) + l15;

  auto rdA = [&](int bufb, int m, int ks) -> s16x8 {
    return *(const s16x8*)(smemc + bufb + ((arow0 + (m << 4)) << 7) +
                           (((ks << 6) + (lhi << 4)) ^ swz));
  };
  auto rdB = [&](int bufb, int n, int ks) -> s16x8 {
    return *(const s16x8*)(smemc + bufb + 32768 + ((brow0 + (n << 4)) << 7) +
                           (((ks << 6) + (lhi << 4)) ^ swz));
  };
  // staging pairs: i=0 -> rounds 0,1 (rows 0..127); i=1 -> rounds 2,3 (rows 128..255)
  auto stgA = [&](int t, int i) {
    const int bb = (t & 1) << 15;
    const size_t go = (size_t)t << 6;
    GLL(gA + go + ((size_t)(2 * i)     << 16), smem + bb + ((2 * i)     << 12) + ldst);
    GLL(gA + go + ((size_t)(2 * i + 1) << 16), smem + bb + ((2 * i + 1) << 12) + ldst);
  };
  auto stgB = [&](int t, int i) {
    const int bb = (t & 1) << 15;
    const size_t go = (size_t)t << 6;
    GLL(gB + go + ((size_t)(2 * i)     << 16), smem + bb + 16384 + ((2 * i)     << 12) + ldst);
    GLL(gB + go + ((size_t)(2 * i + 1) << 16), smem + bb + 16384 + ((2 * i + 1) << 12) + ldst);
  };

  f32x4 acc[8][4] = {};

  // prologue: stage tiles 0 and 1 (FIFO: A(0)x4,B(0)x4,A(1)x4,B(1)x4)
  stgA(0, 0); stgA(0, 1); stgB(0, 0); stgB(0, 1);
  stgA(1, 0); stgA(1, 1); stgB(1, 0); stgB(1, 1);

#pragma unroll 1
  for (int t = 0; t < 16; ++t) {
    if (t == 15) asm volatile("s_waitcnt vmcnt(0)" ::: "memory");
    else         asm volatile("s_waitcnt vmcnt(8)" ::: "memory");
    SB0();
    asm volatile("s_barrier" ::: "memory");
    SB0();
    const int bufb = (t & 1) << 16;

    s16x8 afl[4][2], afh[4][2], bfr[4][2];
    // ---- cluster 1: A-lo frags + B n0-1; 16 MFMA ----
#pragma unroll
    for (int m = 0; m < 4; ++m) { afl[m][0] = rdA(bufb, m, 0); afl[m][1] = rdA(bufb, m, 1); }
#pragma unroll
    for (int n = 0; n < 2; ++n) { bfr[n][0] = rdB(bufb, n, 0); bfr[n][1] = rdB(bufb, n, 1); }
    __builtin_amdgcn_s_setprio(1);
#pragma unroll
    for (int ks = 0; ks < 2; ++ks)
#pragma unroll
      for (int m = 0; m < 4; ++m)
#pragma unroll
        for (int n = 0; n < 2; ++n)
          acc[m][n] = __builtin_amdgcn_mfma_f32_16x16x32_bf16(afl[m][ks], bfr[n][ks], acc[m][n], 0, 0, 0);
    __builtin_amdgcn_s_setprio(0);

    // ---- cluster 2: B n2-3; 16 MFMA ----
#pragma unroll
    for (int n = 2; n < 4; ++n) { bfr[n][0] = rdB(bufb, n, 0); bfr[n][1] = rdB(bufb, n, 1); }
    __builtin_amdgcn_s_setprio(1);
#pragma unroll
    for (int ks = 0; ks < 2; ++ks)
#pragma unroll
      for (int m = 0; m < 4; ++m)
#pragma unroll
        for (int n = 0; n < 2; ++n)
          acc[m][n + 2] = __builtin_amdgcn_mfma_f32_16x16x32_bf16(afl[m][ks], bfr[n + 2][ks], acc[m][n + 2], 0, 0, 0);
    __builtin_amdgcn_s_setprio(0);

    // ---- A-hi frags; mid-tile buffer-free proof ----
#pragma unroll
    for (int m = 0; m < 4; ++m) { afh[m][0] = rdA(bufb, m + 4, 0); afh[m][1] = rdA(bufb, m + 4, 1); }
    asm volatile("s_waitcnt lgkmcnt(0)" ::: "memory");
    SB0();
    asm volatile("s_barrier" ::: "memory");
    SB0();

    // ---- post-mid: 3 MFMA clusters (16/8/8) with 4 staging slots between ----
    if (t < 14) stgA(t + 2, 0);
    SB0();
    __builtin_amdgcn_s_setprio(1);
#pragma unroll
    for (int ks = 0; ks < 2; ++ks)
#pragma unroll
      for (int m = 0; m < 4; ++m)
#pragma unroll
        for (int n = 0; n < 2; ++n)
          acc[m + 4][n + 2] = __builtin_amdgcn_mfma_f32_16x16x32_bf16(afh[m][ks], bfr[n + 2][ks], acc[m + 4][n + 2], 0, 0, 0);
    __builtin_amdgcn_s_setprio(0);
    SB0();
    if (t < 14) stgA(t + 2, 1);
    SB0();
    __builtin_amdgcn_s_setprio(1);
#pragma unroll
    for (int m = 0; m < 4; ++m)
#pragma unroll
      for (int n = 0; n < 2; ++n)
        acc[m + 4][n] = __builtin_amdgcn_mfma_f32_16x16x32_bf16(afh[m][0], bfr[n][0], acc[m + 4][n], 0, 0, 0);
    __builtin_amdgcn_s_setprio(0);
    SB0();
    if (t < 14) stgB(t + 2, 0);
    SB0();
    __builtin_amdgcn_s_setprio(1);
#pragma unroll
    for (int m = 0; m < 4; ++m)
#pragma unroll
      for (int n = 0; n < 2; ++n)
        acc[m + 4][n] = __builtin_amdgcn_mfma_f32_16x16x32_bf16(afh[m][1], bfr[n][1], acc[m + 4][n], 0, 0, 0);
    __builtin_amdgcn_s_setprio(0);
    SB0();
    if (t < 14) stgB(t + 2, 1);
    SB0();
  }

  // close the loop: all waves done reading buf1 before epilogue overwrites LDS
  asm volatile("s_waitcnt lgkmcnt(0)" ::: "memory");
  SB0();
  asm volatile("s_barrier" ::: "memory");
  SB0();

  // --- epilogue: in-register gating (acc[m][2u]=proj, acc[m][2u+1]=gate) ---
  u16* xg = smem;  // [256][136] bf16 (+8 pad), 69632 B
  float bi[2], bg[2];
#pragma unroll
  for (int u = 0; u < 2; ++u) {
    const int gcol = (nb << 7) + (((wn << 1) + u) << 4) + l15;
    bi[u] = b_in[gcol];
    bg[u] = b_gate[gcol];
  }
#pragma unroll
  for (int m = 0; m < 8; ++m)
#pragma unroll
    for (int u = 0; u < 2; ++u)
#pragma unroll
      for (int j = 0; j < 4; ++j) {
        const int row = (wm << 7) + (m << 4) + (lhi << 2) + j;
        const int col = (((wn << 1) + u) << 4) + l15;
        float pv = acc[m][2 * u][j] + bi[u];
        float gv = acc[m][2 * u + 1][j] + bg[u];
        xg[row * 136 + col] = f2b(pv / (1.0f + __expf(-gv)));
      }
  asm volatile("s_waitcnt lgkmcnt(0)" ::: "memory");
  asm volatile("s_barrier" ::: "memory");

  // --- mini-GEMM: Bpart[nb][m0+row][state] = xg @ W_B[:, nb*128..+128]^T ---
  f32x4 bacc[2] = {};
#pragma unroll
  for (int m2 = 0; m2 < 2; ++m2)
#pragma unroll
    for (int kc = 0; kc < 4; ++kc) {
      s16x8 av = *(const s16x8*)(xg + ((wid << 5) + (m2 << 4) + l15) * 136 + (kc << 5) + (lhi << 3));
      s16x8 bv = *(const s16x8*)(WBb + (size_t)l15 * DINNER + (nb << 7) + (kc << 5) + (lhi << 3));
      bacc[m2] = __builtin_amdgcn_mfma_f32_16x16x32_bf16(av, bv, bacc[m2], 0, 0, 0);
    }
#pragma unroll
  for (int m2 = 0; m2 < 2; ++m2) {
    float* outp = Bpart + ((size_t)nb * TOKENS + m0 + (wid << 5) + (m2 << 4) + (lhi << 2)) * NSTATE + l15;
#pragma unroll
    for (int j = 0; j < 4; ++j) outp[j * NSTATE] = bacc[m2][j];
  }
}

// ---------------- C = XP @ W_C^T + b_C (MFMA; W_C staged once in LDS) ----------------
__global__ __launch_bounds__(256) void k_C(const u16* __restrict__ XP, const u16* __restrict__ WC,
                                           const float* __restrict__ bC, float* __restrict__ Cb) {
  __shared__ __align__(16) u16 wcl[16 * 1032];  // rows padded +8 elems
  const int tid = threadIdx.x;
  const int m0 = blockIdx.x << 6;
#pragma unroll
  for (int i = 0; i < 8; ++i) {
    int c = i * 256 + tid;                       // 16B chunk id, 0..2047
    int row = c >> 7, col = c & 127;
    *(u16x8*)(wcl + row * 1032 + (col << 3)) = *(const u16x8*)(WC + (row << 10) + (col << 3));
  }
  __syncthreads();
  const int wv = tid >> 6, lane = tid & 63;
  const int l15 = lane & 15, lhi = lane >> 4;
  const u16* xr = XP + (size_t)(m0 + (wv << 4) + l15) * DMODEL + (lhi << 3);
  const u16* wr = wcl + l15 * 1032 + (lhi << 3);
  f32x4 acc = {};
#pragma unroll
  for (int t = 0; t < 32; ++t) {
    s16x8 av = *(const s16x8*)(xr + t * 32);
    s16x8 bv = *(const s16x8*)(wr + t * 32);
    acc = __builtin_amdgcn_mfma_f32_16x16x32_bf16(av, bv, acc, 0, 0, 0);
  }
  const float bc = bC[l15];
  float* o = Cb + (size_t)(m0 + (wv << 4) + (lhi << 2)) * NSTATE + l15;
#pragma unroll
  for (int j = 0; j < 4; ++j) o[j * NSTATE] = acc[j] + bc;
}

// ---------------- B = sum_chunks Bpart + b_B ----------------
__global__ void k_finB(const float* __restrict__ Bpart, const float* __restrict__ bB,
                       float* __restrict__ Bf) {
  const long i = (long)blockIdx.x * blockDim.x + threadIdx.x;  // per float4
  f32x4 s = {};
#pragma unroll
  for (int cb = 0; cb < 16; ++cb)
    s += *(const f32x4*)(Bpart + (size_t)cb * (TOKENS * NSTATE) + i * 4);
  s += *(const f32x4*)(bB + ((i & 3) << 2));
  *(f32x4*)(Bf + i * 4) = s;
}

// ---------------- sequential scan: h = A*h + B; y = h*C ----------------
__global__ void k_scan(const float* __restrict__ Bf, const float* __restrict__ Cb,
                       const float* __restrict__ Alog, float* __restrict__ Y) {
  const int t = threadIdx.x;
  const int b = blockIdx.x * 16 + (t >> 4);
  const int n = t & 15;
  const float A = __expf(0.01f * __expf(Alog[n]));
  float h = 0.f;
  const size_t base = (size_t)b * SEQLEN * NSTATE + n;
  for (int s = 0; s < SEQLEN; ++s) {
    const size_t idx = base + (size_t)s * NSTATE;
    h = A * h + Bf[idx];
    Y[idx] = h * Cb[idx];
  }
}

// ---------------- out = Y @ W_out[:, :16]^T + b_out ----------------
__global__ __launch_bounds__(256) void k_out(const float* __restrict__ Y,
                                             const float* __restrict__ Wout,
                                             const float* __restrict__ bout,
                                             float* __restrict__ out) {
  __shared__ float ys[32][16];
  const int tid = threadIdx.x;
  const long t0 = (long)blockIdx.x * 32;
  for (int i = tid; i < 512; i += 256) ys[i >> 4][i & 15] = Y[t0 * 16 + i];
  const int d0 = tid << 2;
  float w[4][16];
#pragma unroll
  for (int j = 0; j < 4; ++j)
#pragma unroll
    for (int q = 0; q < 4; ++q) {
      f32x4 wv = *(const f32x4*)(Wout + (size_t)(d0 + j) * DINNER + q * 4);
#pragma unroll
      for (int e = 0; e < 4; ++e) w[j][q * 4 + e] = wv[e];
    }
  f32x4 bo = *(const f32x4*)(bout + d0);
  __syncthreads();
  for (int r = 0; r < 32; ++r) {
    f32x4 acc = bo;
#pragma unroll
    for (int n = 0; n < 16; ++n) {
      const float yv = ys[r][n];
      acc[0] += yv * w[0][n];
      acc[1] += yv * w[1][n];
      acc[2] += yv * w[2][n];
      acc[3] += yv * w[3][n];
    }
    *(f32x4*)(out + (t0 + r) * 1024 + d0) = acc;
  }
}

extern "C" void kernel_launch(void* const* d_in, const int* in_sizes, int n_in,
                              void* d_out, int out_size, void* d_ws, size_t ws_size,
                              hipStream_t stream) {
  const float* x    = (const float*)d_in[0];
  const float* pos  = (const float*)d_in[1];
  const float* Win  = (const float*)d_in[2];
  const float* bin  = (const float*)d_in[3];
  const float* Wg   = (const float*)d_in[4];
  const float* bg   = (const float*)d_in[5];
  const float* Alog = (const float*)d_in[6];
  const float* WB   = (const float*)d_in[7];
  const float* bB   = (const float*)d_in[8];
  const float* WC   = (const float*)d_in[9];
  const float* bC   = (const float*)d_in[10];
  const float* Wout = (const float*)d_in[11];
  const float* bout = (const float*)d_in[12];

  char* ws = (char*)d_ws;
  u16*   XP   = (u16*)(ws + OFF_XP);
  u16*   W2   = (u16*)(ws + OFF_WCAT);
  u16*   WBb  = (u16*)(ws + OFF_WB);
  u16*   WCb  = (u16*)(ws + OFF_WC);
  float* BP   = (float*)(ws + OFF_BPART);
  float* BF   = (float*)(ws + OFF_BFIN);
  float* CB   = (float*)(ws + OFF_CBUF);
  float* Yb   = (float*)(ws + OFF_Y);

  hipFuncSetAttribute((const void*)k_gemm256,
                      hipFuncAttributeMaxDynamicSharedMemorySize, 131072);

  k_prep_x  <<<25600, 256, 0, stream>>>(x, pos, XP);
  k_prep_w  <<<2048, 256, 0, stream>>>(Win, Wg, W2);
  k_prep_wbc<<<24, 256, 0, stream>>>(WB, WC, WBb, WCb);
  k_gemm256 <<<3200, 512, 131072, stream>>>(XP, W2, WBb, bin, bg, BP);
  k_C       <<<800, 256, 0, stream>>>(XP, WCb, bC, CB);
  k_finB    <<<800, 256, 0, stream>>>(BP, bB, BF);
  k_scan    <<<32, 256, 0, stream>>>(BF, CB, Alog, Yb);
  k_out     <<<1600, 256, 0, stream>>>(Yb, Wout, bout, (float*)d_out);
}